// Round 6
// baseline (520.063 us; speedup 1.0000x reference)
//
#include <hip/hip_runtime.h>

#define NN 100000
#define DD 128
#define RR 8
#define NSEG (RR*NN)          // 800000 segments (etype*N + dst)
#define NB1 782               // ceil(NSEG/1024)

typedef unsigned short u16;
typedef __bf16 bf16x8 __attribute__((ext_vector_type(8)));
typedef float f32x4 __attribute__((ext_vector_type(4)));
typedef u16 ushort4e __attribute__((ext_vector_type(4)));   // NT-builtin-compatible
typedef unsigned int uint4e __attribute__((ext_vector_type(4)));

__device__ __forceinline__ u16 f2bf(float f){
    union { float f; unsigned u; } v; v.f = f;
    unsigned r = v.u + 0x7fffu + ((v.u >> 16) & 1u);
    return (u16)(r >> 16);
}
__device__ __forceinline__ float bf2f(u16 h){
    union { unsigned u; float f; } v; v.u = ((unsigned)h) << 16; return v.f;
}
__device__ __forceinline__ float ftanh(float x){
    float e = __expf(2.0f * x);          // inf-safe: x>>0 -> 1, x<<0 -> -1
    return 1.0f - 2.0f / (e + 1.0f);
}
__device__ __forceinline__ bf16x8 ldv(const u16* p){
    return *reinterpret_cast<const bf16x8*>(p);
}

// ---- prep: cast x to bf16 ----
__global__ void k_cast_x(const float* __restrict__ x, u16* __restrict__ xb, int n){
    int i = (blockIdx.x * 256 + threadIdx.x) * 4;
    if (i >= n) return;
    float4 v = *reinterpret_cast<const float4*>(x + i);
    ushort4 o = make_ushort4(f2bf(v.x), f2bf(v.y), f2bf(v.z), f2bf(v.w));
    *reinterpret_cast<ushort4*>(xb + i) = o;
}

// ---- prep: transpose weights to out-major bf16 (B-fragment friendly) ----
__global__ void k_prep_w(const float* __restrict__ Wrel, const float* __restrict__ loopw,
                         const float* __restrict__ W1, const float* __restrict__ W2,
                         u16* __restrict__ WT, u16* __restrict__ W1t, u16* __restrict__ W2t){
    int tid = blockIdx.x * 256 + threadIdx.x;   // grid 1024*256 = 262144 exactly
    if (tid < 131072) {
        int r = tid >> 14, rem = tid & 16383, d = rem >> 7, o = rem & 127;
        WT[(r * 128 + o) * 128 + d] = f2bf(Wrel[tid]);
    } else if (tid < 147456) {
        int i = tid - 131072, d = i >> 7, o = i & 127;
        WT[(8 * 128 + o) * 128 + d] = f2bf(loopw[i]);
    } else if (tid < 212992) {
        int i = tid - 147456, k = i >> 8, n2 = i & 255;
        W1t[n2 * 256 + k] = f2bf(W1[i]);
    } else {
        int i = tid - 212992, k = i >> 7, n2 = i & 127;
        W2t[n2 * 384 + k] = f2bf(W2[i]);
    }
}

// ---- CSR build ----
// count + cache the combined segment id for k_scatter (saves re-reading et/dst)
__global__ void k_count(const int* __restrict__ et, const int* __restrict__ dst,
                        int* __restrict__ cnt, int* __restrict__ seg, int E){
    int e = blockIdx.x * 256 + threadIdx.x;
    if (e < E){
        int s = et[e] * NN + dst[e];
        seg[e] = s;
        atomicAdd(&cnt[s], 1);
    }
}

__global__ void k_scan1(const int* __restrict__ cnt, int* __restrict__ Off, int* __restrict__ bsum){
    __shared__ int lds[256];
    int t = threadIdx.x;
    int i0 = blockIdx.x * 1024 + t * 4;
    int c0 = (i0 + 0 < NSEG) ? cnt[i0 + 0] : 0;
    int c1 = (i0 + 1 < NSEG) ? cnt[i0 + 1] : 0;
    int c2 = (i0 + 2 < NSEG) ? cnt[i0 + 2] : 0;
    int c3 = (i0 + 3 < NSEG) ? cnt[i0 + 3] : 0;
    int s = c0 + c1 + c2 + c3;
    lds[t] = s; __syncthreads();
    for (int off = 1; off < 256; off <<= 1){
        int v = (t >= off) ? lds[t - off] : 0;
        __syncthreads();
        lds[t] += v;
        __syncthreads();
    }
    int excl = lds[t] - s;
    if (i0 + 0 < NSEG) Off[i0 + 0] = excl; excl += c0;
    if (i0 + 1 < NSEG) Off[i0 + 1] = excl; excl += c1;
    if (i0 + 2 < NSEG) Off[i0 + 2] = excl; excl += c2;
    if (i0 + 3 < NSEG) Off[i0 + 3] = excl;
    if (t == 255) bsum[blockIdx.x] = lds[255];
}

__global__ void k_scan2(int* __restrict__ bsum){
    __shared__ int lds[1024];
    int t = threadIdx.x;
    int v = (t < NB1) ? bsum[t] : 0;
    lds[t] = v; __syncthreads();
    for (int off = 1; off < 1024; off <<= 1){
        int u = (t >= off) ? lds[t - off] : 0;
        __syncthreads();
        lds[t] += u;
        __syncthreads();
    }
    if (t < NB1) bsum[t] = lds[t] - v;   // exclusive block base
}

__global__ void k_scan3(int* __restrict__ Off, const int* __restrict__ bsum,
                        int* __restrict__ cursor, int E){
    int base = bsum[blockIdx.x];
    int t = threadIdx.x;
    int i0 = blockIdx.x * 1024 + t * 4;
    #pragma unroll
    for (int j = 0; j < 4; ++j){
        int i = i0 + j;
        if (i < NSEG){ int v = Off[i] + base; Off[i] = v; cursor[i] = v; }
    }
    if (blockIdx.x == 0 && t == 0) Off[NSEG] = E;
}

__global__ void k_scatter(const int* __restrict__ seg, const int* __restrict__ src,
                          int* __restrict__ cursor, int* __restrict__ esrc, int E){
    int e = blockIdx.x * 256 + threadIdx.x;
    if (e < E){
        int pos = atomicAdd(&cursor[seg[e]], 1);
        esrc[pos] = src[e];
    }
}

// ---- standalone gather-aggregate: half-wave per segment, high occupancy ----
// NT stores: the 205 MB agg stream must not thrash L3 (round-3 FETCH showed
// 197 MB of xb re-fetch caused by exactly that).
__global__ __launch_bounds__(256) void k_agg(
    const u16* __restrict__ xb, const int* __restrict__ Off,
    const int* __restrict__ esrc, u16* __restrict__ agg)
{
    int tid = threadIdx.x;
    int half = tid >> 5;                 // 0..7
    int lid  = tid & 31;
    int s = blockIdx.x * 8 + half;       // grid = NSEG/8 exact
    int lo = Off[s], hi = Off[s + 1];
    int cnt = hi - lo;
    const int c = lid * 4;
    float a0 = 0.f, a1 = 0.f, a2 = 0.f, a3 = 0.f;
    // prefetch up to 6 src ids, then gather rows with full ILP
    int sv[6];
    #pragma unroll
    for (int j = 0; j < 6; ++j) sv[j] = (j < cnt) ? esrc[lo + j] : 0;
    #pragma unroll
    for (int j = 0; j < 6; ++j){
        if (j < cnt){
            ushort4 v = *reinterpret_cast<const ushort4*>(xb + (size_t)sv[j] * DD + c);
            a0 += bf2f(v.x); a1 += bf2f(v.y); a2 += bf2f(v.z); a3 += bf2f(v.w);
        }
    }
    for (int e = lo + 6; e < hi; ++e){
        int svv = esrc[e];
        ushort4 v = *reinterpret_cast<const ushort4*>(xb + (size_t)svv * DD + c);
        a0 += bf2f(v.x); a1 += bf2f(v.y); a2 += bf2f(v.z); a3 += bf2f(v.w);
    }
    ushort4e o;
    o.x = f2bf(a0); o.y = f2bf(a1); o.z = f2bf(a2); o.w = f2bf(a3);
    __builtin_nontemporal_store(o, reinterpret_cast<ushort4e*>(agg + (size_t)s * DD + c));
}

// ---- fused MFMA: 9 rel GEMMs (streamed agg tiles) -> MLP1 -> MLP2 ----
// 64-node tile, 512 threads = 8 waves; double-buffered coalesced tile staging.
// LDS 52224 B -> 3 blocks/CU.
__global__ __launch_bounds__(512) void k_fused(
    const u16* __restrict__ xb, const u16* __restrict__ agg,
    const u16* __restrict__ WT, const u16* __restrict__ W1t, const u16* __restrict__ W2t,
    const float* __restrict__ relb, const float* __restrict__ bb1, const float* __restrict__ bb2,
    float* __restrict__ out)
{
    __shared__ __align__(16) u16 smem[26112];
    u16 (*bufA)[136] = (u16(*)[136])(smem);
    u16 (*bufB)[136] = (u16(*)[136])(smem + 8704);
    u16 (*msgs)[136] = (u16(*)[136])(smem + 17408);
    u16 (*mids)[264] = (u16(*)[264])(smem + 8704);

    const int tid = threadIdx.x;
    const int w = tid >> 6;          // wave 0..7
    const int lane = tid & 63;
    const int l15 = lane & 15;
    const int l4 = lane >> 4;        // 0..3
    const int kof = l4 * 8;
    const int b64 = blockIdx.x * 64;

    // coalesced 16 KB tile copy: 512 threads, 8 threads/row x 32 B
    const int srow = tid >> 3;       // 0..63
    const int scg  = (tid & 7) * 16; // u16 col: 0,16,...,112
    auto stage_agg = [&](u16 (*buf)[136], int r){
        int node = b64 + srow;
        uint4e* p = reinterpret_cast<uint4e*>(&buf[srow][scg]);
        if (node < NN){
            const uint4e* g = reinterpret_cast<const uint4e*>(agg + ((size_t)r * NN + node) * DD + scg);
            p[0] = __builtin_nontemporal_load(g);       // read-once chip-wide
            p[1] = __builtin_nontemporal_load(g + 1);
        } else {
            uint4e z = (uint4e)0u;
            p[0] = z; p[1] = z;
        }
    };
    auto stage_x = [&](u16 (*buf)[136]){
        int node = b64 + srow;
        uint4* p = reinterpret_cast<uint4*>(&buf[srow][scg]);
        if (node < NN){
            const uint4* g = reinterpret_cast<const uint4*>(xb + (size_t)node * DD + scg);
            p[0] = g[0];
            p[1] = g[1];
        } else {
            uint4 z = make_uint4(0, 0, 0, 0);
            p[0] = z; p[1] = z;
        }
    };

    // ---------- phase B: msg = sum_r agg_r @ W_r + x @ loop_w ----------
    f32x4 acc[4];
    #pragma unroll
    for (int mi = 0; mi < 4; ++mi)
        #pragma unroll
        for (int q = 0; q < 4; ++q) acc[mi][q] = 0.f;

    stage_agg(bufA, 0);
    __syncthreads();

    for (int r = 0; r <= 8; ++r){
        // stage r+1 into the other buffer (loads fly under this r's MFMAs)
        if (r < 7)       stage_agg((r & 1) ? bufA : bufB, r + 1);
        else if (r == 7) stage_x(bufA);          // x-tile -> bufA (survives for C/D)
        const u16 (*A)[136] = (r & 1) ? bufB : bufA;
        const u16* B = WT + r * (DD * DD);
        #pragma unroll
        for (int kc = 0; kc < 4; ++kc){
            bf16x8 a0 = ldv(&A[l15][kc * 32 + kof]);
            bf16x8 a1 = ldv(&A[16 + l15][kc * 32 + kof]);
            bf16x8 a2 = ldv(&A[32 + l15][kc * 32 + kof]);
            bf16x8 a3 = ldv(&A[48 + l15][kc * 32 + kof]);
            bf16x8 wv = ldv(B + (w * 16 + l15) * DD + kc * 32 + kof);
            acc[0] = __builtin_amdgcn_mfma_f32_16x16x32_bf16(a0, wv, acc[0], 0, 0, 0);
            acc[1] = __builtin_amdgcn_mfma_f32_16x16x32_bf16(a1, wv, acc[1], 0, 0, 0);
            acc[2] = __builtin_amdgcn_mfma_f32_16x16x32_bf16(a2, wv, acc[2], 0, 0, 0);
            acc[3] = __builtin_amdgcn_mfma_f32_16x16x32_bf16(a3, wv, acc[3], 0, 0, 0);
        }
        __syncthreads();
    }

    {   // msgs <- acc + bias   (wave owns cols [16w, 16w+16))
        int col = w * 16 + l15;
        float bv = relb[col];
        #pragma unroll
        for (int mi = 0; mi < 4; ++mi)
            #pragma unroll
            for (int q = 0; q < 4; ++q)
                msgs[mi * 16 + l4 * 4 + q][col] = f2bf(acc[mi][q] + bv);
    }
    __syncthreads();

    // ---------- phase C: mid = tanh([x|msg] @ W1 + b1) ----------
    // wave owns cols [32w, 32w+32); x-tile in bufA, msgs separate
    f32x4 acc2[4][2];
    #pragma unroll
    for (int mi = 0; mi < 4; ++mi)
        #pragma unroll
        for (int nj = 0; nj < 2; ++nj)
            #pragma unroll
            for (int q = 0; q < 4; ++q) acc2[mi][nj][q] = 0.f;

    #pragma unroll
    for (int kc = 0; kc < 8; ++kc){
        bf16x8 a[4];
        #pragma unroll
        for (int mi = 0; mi < 4; ++mi)
            a[mi] = (kc < 4) ? ldv(&bufA[mi * 16 + l15][kc * 32 + kof])
                             : ldv(&msgs[mi * 16 + l15][(kc - 4) * 32 + kof]);
        #pragma unroll
        for (int nj = 0; nj < 2; ++nj){
            int n2 = w * 32 + nj * 16 + l15;
            bf16x8 wv = ldv(W1t + n2 * 256 + kc * 32 + kof);
            #pragma unroll
            for (int mi = 0; mi < 4; ++mi)
                acc2[mi][nj] = __builtin_amdgcn_mfma_f32_16x16x32_bf16(a[mi], wv, acc2[mi][nj], 0, 0, 0);
        }
    }
    __syncthreads();   // all reads of msgs/bufB region done before mids overwrites it
    #pragma unroll
    for (int nj = 0; nj < 2; ++nj){
        int col = w * 32 + nj * 16 + l15;
        float bv = bb1[col];
        #pragma unroll
        for (int mi = 0; mi < 4; ++mi)
            #pragma unroll
            for (int q = 0; q < 4; ++q)
                mids[mi * 16 + l4 * 4 + q][col] = f2bf(ftanh(acc2[mi][nj][q] + bv));
    }
    __syncthreads();

    // ---------- phase D: out = [x|mid] @ W2 + b2 ----------
    // wave owns cols [16w, 16w+16); x in bufA (not aliased by mids)
    f32x4 acc3[4];
    #pragma unroll
    for (int mi = 0; mi < 4; ++mi)
        #pragma unroll
        for (int q = 0; q < 4; ++q) acc3[mi][q] = 0.f;

    #pragma unroll
    for (int kc = 0; kc < 12; ++kc){
        bf16x8 a[4];
        #pragma unroll
        for (int mi = 0; mi < 4; ++mi)
            a[mi] = (kc < 4) ? ldv(&bufA[mi * 16 + l15][kc * 32 + kof])
                             : ldv(&mids[mi * 16 + l15][(kc - 4) * 32 + kof]);
        bf16x8 wv = ldv(W2t + (w * 16 + l15) * 384 + kc * 32 + kof);
        #pragma unroll
        for (int mi = 0; mi < 4; ++mi)
            acc3[mi] = __builtin_amdgcn_mfma_f32_16x16x32_bf16(a[mi], wv, acc3[mi], 0, 0, 0);
    }

    {
        int col = w * 16 + l15;
        float bv = bb2[col];
        #pragma unroll
        for (int mi = 0; mi < 4; ++mi)
            #pragma unroll
            for (int q = 0; q < 4; ++q){
                int row = b64 + mi * 16 + l4 * 4 + q;
                if (row < NN)
                    __builtin_nontemporal_store(acc3[mi][q] + bv,
                        &out[(size_t)row * DD + col]);
            }
    }
}

extern "C" void kernel_launch(void* const* d_in, const int* in_sizes, int n_in,
                              void* d_out, int out_size, void* d_ws, size_t ws_size,
                              hipStream_t stream){
    const float* x    = (const float*)d_in[0];
    const int*   src  = (const int*)d_in[1];
    const int*   dst  = (const int*)d_in[2];
    const int*   et   = (const int*)d_in[3];
    const float* Wrel = (const float*)d_in[4];
    const float* loopw= (const float*)d_in[5];
    const float* relb = (const float*)d_in[6];
    const float* W1   = (const float*)d_in[7];
    const float* b1   = (const float*)d_in[8];
    const float* W2   = (const float*)d_in[9];
    const float* b2   = (const float*)d_in[10];
    const int E = in_sizes[1];
    float* out = (float*)d_out;

    char* ws = (char*)d_ws;
    u16* xb   = (u16*)(ws);                   // 25,600,000 B
    u16* WT   = (u16*)(ws + 25600000);        //    294,912 B
    u16* W1t  = (u16*)(ws + 25894912);        //    131,072 B
    u16* W2t  = (u16*)(ws + 26025984);        //     98,304 B
    int* cnt  = (int*)(ws + 26124288);        //  3,200,000 B (reused as cursor)
    int* Off  = (int*)(ws + 29324288);        //  3,200,256 B (NSEG+1 ints, padded)
    int* bsum = (int*)(ws + 32524544);        //      4,096 B
    int* esrc = (int*)(ws + 32528640);        //  6,400,000 B
    u16* agg  = (u16*)(ws + 38928640);        // 204,800,000 B
    int* seg  = (int*)(ws + 38928640);        // 6,400,000 B — aliases agg head; dead before k_agg writes
    // total required: 243,728,640 B
    if (ws_size < 243728640UL) return;        // fail visibly (zero output)

    hipMemsetAsync(cnt, 0, NSEG * sizeof(int), stream);
    k_cast_x<<<12500, 256, 0, stream>>>(x, xb, NN * DD);
    k_prep_w<<<1024, 256, 0, stream>>>(Wrel, loopw, W1, W2, WT, W1t, W2t);
    k_count<<<(E + 255) / 256, 256, 0, stream>>>(et, dst, cnt, seg, E);
    k_scan1<<<NB1, 256, 0, stream>>>(cnt, Off, bsum);
    k_scan2<<<1, 1024, 0, stream>>>(bsum);
    k_scan3<<<NB1, 256, 0, stream>>>(Off, bsum, cnt, E);
    k_scatter<<<(E + 255) / 256, 256, 0, stream>>>(seg, src, cnt, esrc, E);
    k_agg<<<NSEG / 8, 256, 0, stream>>>(xb, Off, esrc, agg);
    k_fused<<<(NN + 63) / 64, 512, 0, stream>>>(xb, agg, WT, W1t, W2t, relb, b1, b2, out);
}

// Round 7
// 448.138 us; speedup vs baseline: 1.1605x; 1.1605x over previous
//
#include <hip/hip_runtime.h>

#define NN 100000
#define DD 128
#define RR 8
#define NSEG (RR*NN)          // 800000 segments (etype*N + dst)
#define NB1 782               // ceil(NSEG/1024)
#define ECAP 2048             // per-block LDS edge-index cap (32 segs, Poisson(64) -> P(>2048)~0)

typedef unsigned short u16;
typedef __bf16 bf16x8 __attribute__((ext_vector_type(8)));
typedef float f32x4 __attribute__((ext_vector_type(4)));
typedef u16 ushort4e __attribute__((ext_vector_type(4)));   // NT-builtin-compatible
typedef unsigned int uint4e __attribute__((ext_vector_type(4)));

__device__ __forceinline__ u16 f2bf(float f){
    union { float f; unsigned u; } v; v.f = f;
    unsigned r = v.u + 0x7fffu + ((v.u >> 16) & 1u);
    return (u16)(r >> 16);
}
__device__ __forceinline__ float bf2f(u16 h){
    union { unsigned u; float f; } v; v.u = ((unsigned)h) << 16; return v.f;
}
__device__ __forceinline__ float ftanh(float x){
    float e = __expf(2.0f * x);          // inf-safe: x>>0 -> 1, x<<0 -> -1
    return 1.0f - 2.0f / (e + 1.0f);
}
__device__ __forceinline__ bf16x8 ldv(const u16* p){
    return *reinterpret_cast<const bf16x8*>(p);
}

// ---- prep: cast x to bf16 ----
__global__ void k_cast_x(const float* __restrict__ x, u16* __restrict__ xb, int n){
    int i = (blockIdx.x * 256 + threadIdx.x) * 4;
    if (i >= n) return;
    float4 v = *reinterpret_cast<const float4*>(x + i);
    ushort4 o = make_ushort4(f2bf(v.x), f2bf(v.y), f2bf(v.z), f2bf(v.w));
    *reinterpret_cast<ushort4*>(xb + i) = o;
}

// ---- prep: transpose weights to out-major bf16 (B-fragment friendly) ----
__global__ void k_prep_w(const float* __restrict__ Wrel, const float* __restrict__ loopw,
                         const float* __restrict__ W1, const float* __restrict__ W2,
                         u16* __restrict__ WT, u16* __restrict__ W1t, u16* __restrict__ W2t){
    int tid = blockIdx.x * 256 + threadIdx.x;   // grid 1024*256 = 262144 exactly
    if (tid < 131072) {
        int r = tid >> 14, rem = tid & 16383, d = rem >> 7, o = rem & 127;
        WT[(r * 128 + o) * 128 + d] = f2bf(Wrel[tid]);
    } else if (tid < 147456) {
        int i = tid - 131072, d = i >> 7, o = i & 127;
        WT[(8 * 128 + o) * 128 + d] = f2bf(loopw[i]);
    } else if (tid < 212992) {
        int i = tid - 147456, k = i >> 8, n2 = i & 255;
        W1t[n2 * 256 + k] = f2bf(W1[i]);
    } else {
        int i = tid - 212992, k = i >> 7, n2 = i & 127;
        W2t[n2 * 384 + k] = f2bf(W2[i]);
    }
}

// ---- CSR build ----
__global__ void k_count(const int* __restrict__ et, const int* __restrict__ dst,
                        int* __restrict__ cnt, int* __restrict__ seg, int E){
    int e = blockIdx.x * 256 + threadIdx.x;
    if (e < E){
        int s = et[e] * NN + dst[e];
        seg[e] = s;
        atomicAdd(&cnt[s], 1);
    }
}

__global__ void k_scan1(const int* __restrict__ cnt, int* __restrict__ Off, int* __restrict__ bsum){
    __shared__ int lds[256];
    int t = threadIdx.x;
    int i0 = blockIdx.x * 1024 + t * 4;
    int c0 = (i0 + 0 < NSEG) ? cnt[i0 + 0] : 0;
    int c1 = (i0 + 1 < NSEG) ? cnt[i0 + 1] : 0;
    int c2 = (i0 + 2 < NSEG) ? cnt[i0 + 2] : 0;
    int c3 = (i0 + 3 < NSEG) ? cnt[i0 + 3] : 0;
    int s = c0 + c1 + c2 + c3;
    lds[t] = s; __syncthreads();
    for (int off = 1; off < 256; off <<= 1){
        int v = (t >= off) ? lds[t - off] : 0;
        __syncthreads();
        lds[t] += v;
        __syncthreads();
    }
    int excl = lds[t] - s;
    if (i0 + 0 < NSEG) Off[i0 + 0] = excl; excl += c0;
    if (i0 + 1 < NSEG) Off[i0 + 1] = excl; excl += c1;
    if (i0 + 2 < NSEG) Off[i0 + 2] = excl; excl += c2;
    if (i0 + 3 < NSEG) Off[i0 + 3] = excl;
    if (t == 255) bsum[blockIdx.x] = lds[255];
}

__global__ void k_scan2(int* __restrict__ bsum){
    __shared__ int lds[1024];
    int t = threadIdx.x;
    int v = (t < NB1) ? bsum[t] : 0;
    lds[t] = v; __syncthreads();
    for (int off = 1; off < 1024; off <<= 1){
        int u = (t >= off) ? lds[t - off] : 0;
        __syncthreads();
        lds[t] += u;
        __syncthreads();
    }
    if (t < NB1) bsum[t] = lds[t] - v;   // exclusive block base
}

__global__ void k_scan3(int* __restrict__ Off, const int* __restrict__ bsum,
                        int* __restrict__ cursor, int E){
    int base = bsum[blockIdx.x];
    int t = threadIdx.x;
    int i0 = blockIdx.x * 1024 + t * 4;
    #pragma unroll
    for (int j = 0; j < 4; ++j){
        int i = i0 + j;
        if (i < NSEG){ int v = Off[i] + base; Off[i] = v; cursor[i] = v; }
    }
    if (blockIdx.x == 0 && t == 0) Off[NSEG] = E;
}

__global__ void k_scatter(const int* __restrict__ seg, const int* __restrict__ src,
                          int* __restrict__ cursor, int* __restrict__ esrc, int E){
    int e = blockIdx.x * 256 + threadIdx.x;
    if (e < E){
        int pos = atomicAdd(&cursor[seg[e]], 1);
        esrc[pos] = src[e];
    }
}

// ---- block-cooperative gather-aggregate ----
// 256 threads own 32 consecutive segments. Off(33) and the block's contiguous
// esrc range are preloaded coalesced into LDS, so the inner loop's ONLY
// global-latency op is the x-row gather (issued 4-wide). 8 blocks/CU
// -> 256 segments in flight per CU (4x round-5's MLP).
__global__ __launch_bounds__(256) void k_agg(
    const u16* __restrict__ xb, const int* __restrict__ Off,
    const int* __restrict__ esrc, u16* __restrict__ agg)
{
    __shared__ int offs[33];
    __shared__ int eidx[ECAP];
    const int tid = threadIdx.x;
    const int s0 = blockIdx.x * 32;        // grid = NSEG/32 exact
    if (tid < 33) offs[tid] = Off[s0 + tid];
    __syncthreads();
    const int base = offs[0];
    const int tot = offs[32] - base;
    const bool inlds = (tot <= ECAP);
    if (inlds){
        for (int i = tid; i < tot; i += 256) eidx[i] = esrc[base + i];
    }
    __syncthreads();

    const int hw = tid >> 5;               // half-wave 0..7
    const int lid = tid & 31;
    const int c = lid * 4;

    #pragma unroll
    for (int j = 0; j < 4; ++j){
        const int sj = hw * 4 + j;         // segment-in-block 0..31
        const int lo = offs[sj] - base;
        const int hi = offs[sj + 1] - base;
        float a0 = 0.f, a1 = 0.f, a2 = 0.f, a3 = 0.f;
        int e = lo;
        if (inlds){
            for (; e + 4 <= hi; e += 4){   // 4 independent rows in flight
                int i0 = eidx[e], i1 = eidx[e+1], i2 = eidx[e+2], i3 = eidx[e+3];
                ushort4 v0 = *reinterpret_cast<const ushort4*>(xb + (size_t)i0 * DD + c);
                ushort4 v1 = *reinterpret_cast<const ushort4*>(xb + (size_t)i1 * DD + c);
                ushort4 v2 = *reinterpret_cast<const ushort4*>(xb + (size_t)i2 * DD + c);
                ushort4 v3 = *reinterpret_cast<const ushort4*>(xb + (size_t)i3 * DD + c);
                a0 += bf2f(v0.x) + bf2f(v1.x) + bf2f(v2.x) + bf2f(v3.x);
                a1 += bf2f(v0.y) + bf2f(v1.y) + bf2f(v2.y) + bf2f(v3.y);
                a2 += bf2f(v0.z) + bf2f(v1.z) + bf2f(v2.z) + bf2f(v3.z);
                a3 += bf2f(v0.w) + bf2f(v1.w) + bf2f(v2.w) + bf2f(v3.w);
            }
            for (; e < hi; ++e){
                int i = eidx[e];
                ushort4 v = *reinterpret_cast<const ushort4*>(xb + (size_t)i * DD + c);
                a0 += bf2f(v.x); a1 += bf2f(v.y); a2 += bf2f(v.z); a3 += bf2f(v.w);
            }
        } else {                           // fallback: oversize block range
            for (; e < hi; ++e){
                int i = esrc[base + e];
                ushort4 v = *reinterpret_cast<const ushort4*>(xb + (size_t)i * DD + c);
                a0 += bf2f(v.x); a1 += bf2f(v.y); a2 += bf2f(v.z); a3 += bf2f(v.w);
            }
        }
        ushort4e o;
        o.x = f2bf(a0); o.y = f2bf(a1); o.z = f2bf(a2); o.w = f2bf(a3);
        __builtin_nontemporal_store(o,
            reinterpret_cast<ushort4e*>(agg + (size_t)(s0 + sj) * DD + c));
    }
}

// ---- fused MFMA: 9 rel GEMMs (streamed agg tiles) -> MLP1 -> MLP2 ----
// 64-node tile, 512 threads = 8 waves; double-buffered coalesced tile staging.
// LDS 52224 B -> 3 blocks/CU.
__global__ __launch_bounds__(512) void k_fused(
    const u16* __restrict__ xb, const u16* __restrict__ agg,
    const u16* __restrict__ WT, const u16* __restrict__ W1t, const u16* __restrict__ W2t,
    const float* __restrict__ relb, const float* __restrict__ bb1, const float* __restrict__ bb2,
    float* __restrict__ out)
{
    __shared__ __align__(16) u16 smem[26112];
    u16 (*bufA)[136] = (u16(*)[136])(smem);
    u16 (*bufB)[136] = (u16(*)[136])(smem + 8704);
    u16 (*msgs)[136] = (u16(*)[136])(smem + 17408);
    u16 (*mids)[264] = (u16(*)[264])(smem + 8704);

    const int tid = threadIdx.x;
    const int w = tid >> 6;          // wave 0..7
    const int lane = tid & 63;
    const int l15 = lane & 15;
    const int l4 = lane >> 4;        // 0..3
    const int kof = l4 * 8;
    const int b64 = blockIdx.x * 64;

    // coalesced 16 KB tile copy: 512 threads, 8 threads/row x 32 B
    const int srow = tid >> 3;       // 0..63
    const int scg  = (tid & 7) * 16; // u16 col: 0,16,...,112
    auto stage_agg = [&](u16 (*buf)[136], int r){
        int node = b64 + srow;
        uint4e* p = reinterpret_cast<uint4e*>(&buf[srow][scg]);
        if (node < NN){
            const uint4e* g = reinterpret_cast<const uint4e*>(agg + ((size_t)r * NN + node) * DD + scg);
            p[0] = __builtin_nontemporal_load(g);       // read-once chip-wide
            p[1] = __builtin_nontemporal_load(g + 1);
        } else {
            uint4e z = (uint4e)0u;
            p[0] = z; p[1] = z;
        }
    };
    auto stage_x = [&](u16 (*buf)[136]){
        int node = b64 + srow;
        uint4* p = reinterpret_cast<uint4*>(&buf[srow][scg]);
        if (node < NN){
            const uint4* g = reinterpret_cast<const uint4*>(xb + (size_t)node * DD + scg);
            p[0] = g[0];
            p[1] = g[1];
        } else {
            uint4 z = make_uint4(0, 0, 0, 0);
            p[0] = z; p[1] = z;
        }
    };

    // ---------- phase B: msg = sum_r agg_r @ W_r + x @ loop_w ----------
    f32x4 acc[4];
    #pragma unroll
    for (int mi = 0; mi < 4; ++mi)
        #pragma unroll
        for (int q = 0; q < 4; ++q) acc[mi][q] = 0.f;

    stage_agg(bufA, 0);
    __syncthreads();

    for (int r = 0; r <= 8; ++r){
        // stage r+1 into the other buffer (loads fly under this r's MFMAs)
        if (r < 7)       stage_agg((r & 1) ? bufA : bufB, r + 1);
        else if (r == 7) stage_x(bufA);          // x-tile -> bufA (survives for C/D)
        const u16 (*A)[136] = (r & 1) ? bufB : bufA;
        const u16* B = WT + r * (DD * DD);
        #pragma unroll
        for (int kc = 0; kc < 4; ++kc){
            bf16x8 a0 = ldv(&A[l15][kc * 32 + kof]);
            bf16x8 a1 = ldv(&A[16 + l15][kc * 32 + kof]);
            bf16x8 a2 = ldv(&A[32 + l15][kc * 32 + kof]);
            bf16x8 a3 = ldv(&A[48 + l15][kc * 32 + kof]);
            bf16x8 wv = ldv(B + (w * 16 + l15) * DD + kc * 32 + kof);
            acc[0] = __builtin_amdgcn_mfma_f32_16x16x32_bf16(a0, wv, acc[0], 0, 0, 0);
            acc[1] = __builtin_amdgcn_mfma_f32_16x16x32_bf16(a1, wv, acc[1], 0, 0, 0);
            acc[2] = __builtin_amdgcn_mfma_f32_16x16x32_bf16(a2, wv, acc[2], 0, 0, 0);
            acc[3] = __builtin_amdgcn_mfma_f32_16x16x32_bf16(a3, wv, acc[3], 0, 0, 0);
        }
        __syncthreads();
    }

    {   // msgs <- acc + bias   (wave owns cols [16w, 16w+16))
        int col = w * 16 + l15;
        float bv = relb[col];
        #pragma unroll
        for (int mi = 0; mi < 4; ++mi)
            #pragma unroll
            for (int q = 0; q < 4; ++q)
                msgs[mi * 16 + l4 * 4 + q][col] = f2bf(acc[mi][q] + bv);
    }
    __syncthreads();

    // ---------- phase C: mid = tanh([x|msg] @ W1 + b1) ----------
    // wave owns cols [32w, 32w+32); x-tile in bufA, msgs separate
    f32x4 acc2[4][2];
    #pragma unroll
    for (int mi = 0; mi < 4; ++mi)
        #pragma unroll
        for (int nj = 0; nj < 2; ++nj)
            #pragma unroll
            for (int q = 0; q < 4; ++q) acc2[mi][nj][q] = 0.f;

    #pragma unroll
    for (int kc = 0; kc < 8; ++kc){
        bf16x8 a[4];
        #pragma unroll
        for (int mi = 0; mi < 4; ++mi)
            a[mi] = (kc < 4) ? ldv(&bufA[mi * 16 + l15][kc * 32 + kof])
                             : ldv(&msgs[mi * 16 + l15][(kc - 4) * 32 + kof]);
        #pragma unroll
        for (int nj = 0; nj < 2; ++nj){
            int n2 = w * 32 + nj * 16 + l15;
            bf16x8 wv = ldv(W1t + n2 * 256 + kc * 32 + kof);
            #pragma unroll
            for (int mi = 0; mi < 4; ++mi)
                acc2[mi][nj] = __builtin_amdgcn_mfma_f32_16x16x32_bf16(a[mi], wv, acc2[mi][nj], 0, 0, 0);
        }
    }
    __syncthreads();   // all reads of msgs/bufB region done before mids overwrites it
    #pragma unroll
    for (int nj = 0; nj < 2; ++nj){
        int col = w * 32 + nj * 16 + l15;
        float bv = bb1[col];
        #pragma unroll
        for (int mi = 0; mi < 4; ++mi)
            #pragma unroll
            for (int q = 0; q < 4; ++q)
                mids[mi * 16 + l4 * 4 + q][col] = f2bf(ftanh(acc2[mi][nj][q] + bv));
    }
    __syncthreads();

    // ---------- phase D: out = [x|mid] @ W2 + b2 ----------
    // wave owns cols [16w, 16w+16); x in bufA (not aliased by mids)
    f32x4 acc3[4];
    #pragma unroll
    for (int mi = 0; mi < 4; ++mi)
        #pragma unroll
        for (int q = 0; q < 4; ++q) acc3[mi][q] = 0.f;

    #pragma unroll
    for (int kc = 0; kc < 12; ++kc){
        bf16x8 a[4];
        #pragma unroll
        for (int mi = 0; mi < 4; ++mi)
            a[mi] = (kc < 4) ? ldv(&bufA[mi * 16 + l15][kc * 32 + kof])
                             : ldv(&mids[mi * 16 + l15][(kc - 4) * 32 + kof]);
        bf16x8 wv = ldv(W2t + (w * 16 + l15) * 384 + kc * 32 + kof);
        #pragma unroll
        for (int mi = 0; mi < 4; ++mi)
            acc3[mi] = __builtin_amdgcn_mfma_f32_16x16x32_bf16(a[mi], wv, acc3[mi], 0, 0, 0);
    }

    {
        int col = w * 16 + l15;
        float bv = bb2[col];
        #pragma unroll
        for (int mi = 0; mi < 4; ++mi)
            #pragma unroll
            for (int q = 0; q < 4; ++q){
                int row = b64 + mi * 16 + l4 * 4 + q;
                if (row < NN)
                    __builtin_nontemporal_store(acc3[mi][q] + bv,
                        &out[(size_t)row * DD + col]);
            }
    }
}

extern "C" void kernel_launch(void* const* d_in, const int* in_sizes, int n_in,
                              void* d_out, int out_size, void* d_ws, size_t ws_size,
                              hipStream_t stream){
    const float* x    = (const float*)d_in[0];
    const int*   src  = (const int*)d_in[1];
    const int*   dst  = (const int*)d_in[2];
    const int*   et   = (const int*)d_in[3];
    const float* Wrel = (const float*)d_in[4];
    const float* loopw= (const float*)d_in[5];
    const float* relb = (const float*)d_in[6];
    const float* W1   = (const float*)d_in[7];
    const float* b1   = (const float*)d_in[8];
    const float* W2   = (const float*)d_in[9];
    const float* b2   = (const float*)d_in[10];
    const int E = in_sizes[1];
    float* out = (float*)d_out;

    char* ws = (char*)d_ws;
    u16* xb   = (u16*)(ws);                   // 25,600,000 B
    u16* WT   = (u16*)(ws + 25600000);        //    294,912 B
    u16* W1t  = (u16*)(ws + 25894912);        //    131,072 B
    u16* W2t  = (u16*)(ws + 26025984);        //     98,304 B
    int* cnt  = (int*)(ws + 26124288);        //  3,200,000 B (reused as cursor)
    int* Off  = (int*)(ws + 29324288);        //  3,200,256 B (NSEG+1 ints, padded)
    int* bsum = (int*)(ws + 32524544);        //      4,096 B
    int* esrc = (int*)(ws + 32528640);        //  6,400,000 B
    u16* agg  = (u16*)(ws + 38928640);        // 204,800,000 B
    int* seg  = (int*)(ws + 38928640);        // 6,400,000 B — aliases agg head; dead before k_agg writes
    // total required: 243,728,640 B
    if (ws_size < 243728640UL) return;        // fail visibly (zero output)

    hipMemsetAsync(cnt, 0, NSEG * sizeof(int), stream);
    k_cast_x<<<12500, 256, 0, stream>>>(x, xb, NN * DD);
    k_prep_w<<<1024, 256, 0, stream>>>(Wrel, loopw, W1, W2, WT, W1t, W2t);
    k_count<<<(E + 255) / 256, 256, 0, stream>>>(et, dst, cnt, seg, E);
    k_scan1<<<NB1, 256, 0, stream>>>(cnt, Off, bsum);
    k_scan2<<<1, 1024, 0, stream>>>(bsum);
    k_scan3<<<NB1, 256, 0, stream>>>(Off, bsum, cnt, E);
    k_scatter<<<(E + 255) / 256, 256, 0, stream>>>(seg, src, cnt, esrc, E);
    k_agg<<<NSEG / 32, 256, 0, stream>>>(xb, Off, esrc, agg);
    k_fused<<<(NN + 63) / 64, 512, 0, stream>>>(xb, agg, WT, W1t, W2t, relb, b1, b2, out);
}